// Round 1
// baseline (460.050 us; speedup 1.0000x reference)
//
#include <hip/hip_runtime.h>
#include <math.h>

// MoLoRARouter: router_logits = x[16384,4096] @ gate_w[64,4096]^T  (fp32)
// -> softmax over 64 experts -> top-2 -> renormalize.
// Renormalized top-2 weights: softmax denom cancels ->
//   w1 = 1/(1+exp(l2-l1)), w2 = exp(l2-l1)/(1+exp(l2-l1)), l1 >= l2.
// Indices written as float (harness reads whole d_out as float32).

constexpr int Hdim = 4096;   // hidden
constexpr int Edim = 64;     // experts
constexpr int BM   = 64;     // tokens per block
constexpr int BK   = 64;     // K-tile
constexpr int LSTR = 66;     // LDS row stride (floats): 2-way-max bank conflicts, 8B aligned rows
constexpr int PSTR = 68;     // epilogue logits stride (16B-aligned float4 stores)
constexpr int NKT  = Hdim / BK;  // 64 K-tiles
constexpr int NTOK = 16384;      // B*S

__global__ __launch_bounds__(256)
void router_kernel(const float* __restrict__ x,
                   const float* __restrict__ gw,
                   float* __restrict__ out)
{
    __shared__ float lx[2 * BM * LSTR];    // x tiles, double buffered
    __shared__ float lw[2 * Edim * LSTR];  // w tiles, double buffered

    const int tid = threadIdx.x;
    const int t0  = blockIdx.x * BM;

    // staging: thread -> (row = m*16 + srow, cols scol..scol+3), m = 0..3
    const int srow = tid >> 4;          // 0..15
    const int scol = (tid & 15) << 2;   // 0,4,...,60

    // compute: wave-local 8 token-groups x 8 expert-groups (broadcast-friendly)
    const int wave = tid >> 6, lane = tid & 63;
    const int tg = ((wave >> 1) << 3) + (lane >> 3);   // 0..15, 4 tokens each
    const int eg = ((wave & 1) << 3) + (lane & 7);     // 0..15, 4 experts each

    float acc[4][4];
    #pragma unroll
    for (int i = 0; i < 4; ++i)
        #pragma unroll
        for (int j = 0; j < 4; ++j) acc[i][j] = 0.f;

    const float* xg = x + (size_t)t0 * Hdim;

    float4 rx[4], rw[4];
    // prologue: stage tile 0 into buffer 0
    #pragma unroll
    for (int m = 0; m < 4; ++m) {
        const int r = m * 16 + srow;
        rx[m] = *(const float4*)(xg + (size_t)r * Hdim + scol);
        rw[m] = *(const float4*)(gw + (size_t)r * Hdim + scol);
    }
    #pragma unroll
    for (int m = 0; m < 4; ++m) {
        const int r = m * 16 + srow;
        float2* px = (float2*)&lx[r * LSTR + scol];
        px[0] = make_float2(rx[m].x, rx[m].y);
        px[1] = make_float2(rx[m].z, rx[m].w);
        float2* pw = (float2*)&lw[r * LSTR + scol];
        pw[0] = make_float2(rw[m].x, rw[m].y);
        pw[1] = make_float2(rw[m].z, rw[m].w);
    }
    __syncthreads();

    for (int kt = 0; kt < NKT; ++kt) {
        const int cur = (kt & 1) ? BM * LSTR : 0;
        const int nxt = (kt & 1) ? 0 : BM * LSTR;
        const int knext = (kt + 1 < NKT) ? (kt + 1) * BK : 0;  // dummy-reload tile0 on last iter

        // issue next tile's global loads; compute below hides the latency
        #pragma unroll
        for (int m = 0; m < 4; ++m) {
            const int r = m * 16 + srow;
            rx[m] = *(const float4*)(xg + (size_t)r * Hdim + knext + scol);
            rw[m] = *(const float4*)(gw + (size_t)r * Hdim + knext + scol);
        }

        const float* __restrict__ bx = &lx[cur];
        const float* __restrict__ bw = &lw[cur];
        #pragma unroll 8
        for (int k = 0; k < BK; k += 2) {
            float2 xa[4], wb[4];
            #pragma unroll
            for (int i = 0; i < 4; ++i)
                xa[i] = *(const float2*)&bx[(4 * tg + i) * LSTR + k];
            #pragma unroll
            for (int j = 0; j < 4; ++j)
                wb[j] = *(const float2*)&bw[(4 * eg + j) * LSTR + k];
            #pragma unroll
            for (int i = 0; i < 4; ++i)
                #pragma unroll
                for (int j = 0; j < 4; ++j)
                    acc[i][j] = fmaf(xa[i].y, wb[j].y,
                                 fmaf(xa[i].x, wb[j].x, acc[i][j]));
        }

        // write next tile (waitcnt on the global loads lands here, after compute)
        #pragma unroll
        for (int m = 0; m < 4; ++m) {
            const int r = m * 16 + srow;
            float2* px = (float2*)&lx[nxt + r * LSTR + scol];
            px[0] = make_float2(rx[m].x, rx[m].y);
            px[1] = make_float2(rx[m].z, rx[m].w);
            float2* pw = (float2*)&lw[nxt + r * LSTR + scol];
            pw[0] = make_float2(rw[m].x, rw[m].y);
            pw[1] = make_float2(rw[m].z, rw[m].w);
        }
        __syncthreads();
    }

    // epilogue: dump 64x64 logits to LDS (reuse lx), then per-token top-2
    float* lg = lx;
    #pragma unroll
    for (int i = 0; i < 4; ++i) {
        float4 v = make_float4(acc[i][0], acc[i][1], acc[i][2], acc[i][3]);
        *(float4*)&lg[(4 * tg + i) * PSTR + 4 * eg] = v;
    }
    __syncthreads();

    if (tid < BM) {
        const float* row = &lg[tid * PSTR];
        float m1 = -INFINITY, m2 = -INFINITY;
        int i1 = 0, i2 = 0;
        for (int e = 0; e < Edim; ++e) {
            float v = row[e];
            if (v > m1) { m2 = m1; i2 = i1; m1 = v; i1 = e; }   // strict > : lower index wins ties (matches lax.top_k)
            else if (v > m2) { m2 = v; i2 = e; }
        }
        const float r   = expf(m2 - m1);        // in (0,1]
        const float inv = 1.f / (1.f + r);
        const int t = t0 + tid;
        float* ow = out + 2 * (size_t)t;
        ow[0] = inv;            // w1 renormalized
        ow[1] = r * inv;        // w2 renormalized
        float* oi = out + 2 * (size_t)NTOK + 2 * (size_t)t;
        oi[0] = (float)i1;
        oi[1] = (float)i2;
    }
}

extern "C" void kernel_launch(void* const* d_in, const int* in_sizes, int n_in,
                              void* d_out, int out_size, void* d_ws, size_t ws_size,
                              hipStream_t stream) {
    const float* x  = (const float*)d_in[0];   // [4,4096,4096] fp32
    const float* gw = (const float*)d_in[1];   // [64,4096] fp32
    float* out = (float*)d_out;                // weights(32768) ++ indices(32768)
    dim3 grid(NTOK / BM), block(256);
    hipLaunchKernelGGL(router_kernel, grid, block, 0, stream, x, gw, out);
}

// Round 3
// 419.608 us; speedup vs baseline: 1.0964x; 1.0964x over previous
//
#include <hip/hip_runtime.h>
#include <math.h>

// MoLoRARouter: logits = x[16384,4096] @ gate_w[64,4096]^T (fp32) -> softmax
// -> top-2 -> renorm.  fp32 emulated as split-2 fp16 MFMA:
//   v = h + l/2048,  h = fp16(v), l = fp16((v-h)*2048)   (~22-24 mantissa bits)
//   logit = hh + (hl+lh)/2048 + ll/2048^2  -> error ~1e-6, fp32-reorder class.
// Renorm weights: w1 = 1/(1+exp(l2-l1)), w2 = 1-w1. Indices stored as float.
// LDS: XOR-swizzle (group slot = g ^ (row&7), stride 64 halves, no pad):
// every ds_read_b128/ds_write_b128 lands exactly 8 dwords/bank (minimum).
// Separate named __shared__ arrays; dedicated logits array (no alias casts).

typedef _Float16 half8 __attribute__((ext_vector_type(8)));
typedef float floatx4 __attribute__((ext_vector_type(4)));

constexpr int Hdim = 4096;
constexpr int Edim = 64;
constexpr int BM   = 64;           // tokens per block
constexpr int BK   = 64;           // K-chunk (floats)
constexpr int NKT  = Hdim / BK;    // 64 chunks
constexpr int NTOK = 16384;
constexpr int PSTR = 68;           // logits row stride (17 words: odd -> 2-way banks)
constexpr float SCL  = 2048.0f;
constexpr float ISCL = 1.0f / 2048.0f;

__global__ __launch_bounds__(256)
void router_kernel(const float* __restrict__ x,
                   const float* __restrict__ gw,
                   float* __restrict__ out)
{
    // 2 buffers x 64 rows x 64 halves, XOR-swizzled groups. 8 KiB each.
    __shared__ alignas(16) _Float16 sxh[2][BM * BK];
    __shared__ alignas(16) _Float16 sxl[2][BM * BK];
    __shared__ alignas(16) _Float16 swh[2][BM * BK];
    __shared__ alignas(16) _Float16 swl[2][BM * BK];
    __shared__ float slg[BM * PSTR];   // dedicated epilogue logits

    const int tid = threadIdx.x;
    const int t0  = blockIdx.x * BM;

    // staging: thread -> row sr (0..63), column quarter q4 (16 floats)
    const int sr = tid & 63;
    const int q4 = tid >> 6;
    const int sw8 = sr & 7;
    const int a0 = sr * BK + (((2 * q4)     ^ sw8) << 3);  // group 2*q4
    const int a1 = sr * BK + (((2 * q4 + 1) ^ sw8) << 3);  // group 2*q4+1

    // MFMA tiling: 4 waves, each 32 tok x 32 exp (2x2 of 16x16x32)
    const int wv = tid >> 6, lane = tid & 63;
    const int ln15 = lane & 15, quad = lane >> 4;
    const int th = (wv >> 1) * 32;
    const int eh = (wv & 1) * 32;

    const float* xrow = x  + (size_t)(t0 + sr) * Hdim + q4 * 16;
    const float* wrow = gw + (size_t)sr        * Hdim + q4 * 16;

    floatx4 accm[2][2], accc[2][2], accl[2][2];
    #pragma unroll
    for (int a = 0; a < 2; ++a)
        #pragma unroll
        for (int b = 0; b < 2; ++b) {
            accm[a][b] = (floatx4)0.0f;
            accc[a][b] = (floatx4)0.0f;
            accl[a][b] = (floatx4)0.0f;
        }

    float4 rx[4], rw[4];

    // ---- prologue: load + stage chunk 0 into buffer 0 ----
    #pragma unroll
    for (int j = 0; j < 4; ++j) {
        rx[j] = *(const float4*)(xrow + 4 * j);
        rw[j] = *(const float4*)(wrow + 4 * j);
    }
    {
        half8 hx0, hx1, lx0, lx1, hw0, hw1, lw0, lw1;
        #pragma unroll
        for (int j = 0; j < 4; ++j) {
            const float* px = (const float*)&rx[j];
            const float* pw = (const float*)&rw[j];
            #pragma unroll
            for (int c = 0; c < 4; ++c) {
                const int idx = 4 * j + c, g = idx >> 3, o = idx & 7;
                _Float16 h = (_Float16)px[c];
                _Float16 l = (_Float16)((px[c] - (float)h) * SCL);
                if (g == 0) { hx0[o] = h; lx0[o] = l; } else { hx1[o] = h; lx1[o] = l; }
                h = (_Float16)pw[c];
                l = (_Float16)((pw[c] - (float)h) * SCL);
                if (g == 0) { hw0[o] = h; lw0[o] = l; } else { hw1[o] = h; lw1[o] = l; }
            }
        }
        *(half8*)&sxh[0][a0] = hx0;  *(half8*)&sxh[0][a1] = hx1;
        *(half8*)&sxl[0][a0] = lx0;  *(half8*)&sxl[0][a1] = lx1;
        *(half8*)&swh[0][a0] = hw0;  *(half8*)&swh[0][a1] = hw1;
        *(half8*)&swl[0][a0] = lw0;  *(half8*)&swl[0][a1] = lw1;
    }
    __syncthreads();

    for (int kt = 0; kt < NKT; ++kt) {
        const int cur = kt & 1;
        const int nxt = cur ^ 1;
        const int kb  = (kt + 1 < NKT) ? (kt + 1) * BK : 0;  // dummy reload on last

        // issue next chunk's global loads (vmcnt drains during MFMAs below)
        #pragma unroll
        for (int j = 0; j < 4; ++j) {
            rx[j] = *(const float4*)(xrow + kb + 4 * j);
            rw[j] = *(const float4*)(wrow + kb + 4 * j);
        }

        // compute on current buffer: two K=32 sub-steps
        #pragma unroll
        for (int kk = 0; kk < 2; ++kk) {
            half8 ah[2], al[2], bh[2], bl[2];
            #pragma unroll
            for (int mt = 0; mt < 2; ++mt) {
                const int m = th + mt * 16 + ln15;
                const int aA = m * BK + (((kk * 4 + quad) ^ (m & 7)) << 3);
                ah[mt] = *(const half8*)&sxh[cur][aA];
                al[mt] = *(const half8*)&sxl[cur][aA];
            }
            #pragma unroll
            for (int nt = 0; nt < 2; ++nt) {
                const int n = eh + nt * 16 + ln15;
                const int aB = n * BK + (((kk * 4 + quad) ^ (n & 7)) << 3);
                bh[nt] = *(const half8*)&swh[cur][aB];
                bl[nt] = *(const half8*)&swl[cur][aB];
            }
            #pragma unroll
            for (int mt = 0; mt < 2; ++mt)
                #pragma unroll
                for (int nt = 0; nt < 2; ++nt) {
                    accm[mt][nt] = __builtin_amdgcn_mfma_f32_16x16x32_f16(ah[mt], bh[nt], accm[mt][nt], 0, 0, 0);
                    accc[mt][nt] = __builtin_amdgcn_mfma_f32_16x16x32_f16(ah[mt], bl[nt], accc[mt][nt], 0, 0, 0);
                    accc[mt][nt] = __builtin_amdgcn_mfma_f32_16x16x32_f16(al[mt], bh[nt], accc[mt][nt], 0, 0, 0);
                    accl[mt][nt] = __builtin_amdgcn_mfma_f32_16x16x32_f16(al[mt], bl[nt], accl[mt][nt], 0, 0, 0);
                }
        }

        // stage next chunk
        {
            half8 hx0, hx1, lx0, lx1, hw0, hw1, lw0, lw1;
            #pragma unroll
            for (int j = 0; j < 4; ++j) {
                const float* px = (const float*)&rx[j];
                const float* pw = (const float*)&rw[j];
                #pragma unroll
                for (int c = 0; c < 4; ++c) {
                    const int idx = 4 * j + c, g = idx >> 3, o = idx & 7;
                    _Float16 h = (_Float16)px[c];
                    _Float16 l = (_Float16)((px[c] - (float)h) * SCL);
                    if (g == 0) { hx0[o] = h; lx0[o] = l; } else { hx1[o] = h; lx1[o] = l; }
                    h = (_Float16)pw[c];
                    l = (_Float16)((pw[c] - (float)h) * SCL);
                    if (g == 0) { hw0[o] = h; lw0[o] = l; } else { hw1[o] = h; lw1[o] = l; }
                }
            }
            *(half8*)&sxh[nxt][a0] = hx0;  *(half8*)&sxh[nxt][a1] = hx1;
            *(half8*)&sxl[nxt][a0] = lx0;  *(half8*)&sxl[nxt][a1] = lx1;
            *(half8*)&swh[nxt][a0] = hw0;  *(half8*)&swh[nxt][a1] = hw1;
            *(half8*)&swl[nxt][a0] = lw0;  *(half8*)&swl[nxt][a1] = lw1;
        }
        __syncthreads();
    }

    // ---- epilogue: combine split terms -> dedicated logits LDS -> top-2 ----
    #pragma unroll
    for (int mt = 0; mt < 2; ++mt)
        #pragma unroll
        for (int nt = 0; nt < 2; ++nt)
            #pragma unroll
            for (int i = 0; i < 4; ++i) {
                const float v = accm[mt][nt][i] + accc[mt][nt][i] * ISCL
                              + accl[mt][nt][i] * (ISCL * ISCL);
                const int r = th + mt * 16 + quad * 4 + i;   // D: row = quad*4+reg
                const int c = eh + nt * 16 + ln15;           // D: col = lane&15
                slg[r * PSTR + c] = v;
            }
    __syncthreads();

    if (tid < BM) {
        const float* row = &slg[tid * PSTR];
        float m1 = -INFINITY, m2 = -INFINITY;
        int i1 = 0, i2 = 0;
        for (int e = 0; e < Edim; ++e) {
            float v = row[e];
            if (v > m1) { m2 = m1; i2 = i1; m1 = v; i1 = e; }  // strict >: lower index wins ties
            else if (v > m2) { m2 = v; i2 = e; }
        }
        const float r   = expf(m2 - m1);
        const float inv = 1.f / (1.f + r);
        const int t = t0 + tid;
        float* ow = out + 2 * (size_t)t;
        ow[0] = inv;
        ow[1] = r * inv;
        float* oi = out + 2 * (size_t)NTOK + 2 * (size_t)t;
        oi[0] = (float)i1;
        oi[1] = (float)i2;
    }
}

extern "C" void kernel_launch(void* const* d_in, const int* in_sizes, int n_in,
                              void* d_out, int out_size, void* d_ws, size_t ws_size,
                              hipStream_t stream) {
    const float* x  = (const float*)d_in[0];   // [4,4096,4096] fp32
    const float* gw = (const float*)d_in[1];   // [64,4096] fp32
    float* out = (float*)d_out;                // weights(32768) ++ indices(32768)
    dim3 grid(NTOK / BM), block(256);
    hipLaunchKernelGGL(router_kernel, grid, block, 0, stream, x, gw, out);
}